// Round 7
// baseline (91393.854 us; speedup 1.0000x reference)
//
#include <hip/hip_runtime.h>
#include <stdint.h>

typedef unsigned short u16;
typedef unsigned int u32;
typedef unsigned long long u64;

#define B_ 64
#define T_ 512
#define N_ 128
#define H_ 512
#define KDIM 640        // H + N
#define PITCH 648       // LDS row stride (u16) for weight slice
#define SGP 65          // gate LDS pitch (fp32)
#define NSLOT 32        // WGs per XCD
#define NXCD 8
#define FL 32           // u32 per 128B flag line
// sync lines: [0..7]=orgcnt per xcd; [8..263]=local flags (xcd*32+s); [264..519]=LLC flags
#define LF_BASE 8
#define GF_BASE 264

typedef __attribute__((ext_vector_type(8))) short short8;
typedef __attribute__((ext_vector_type(4))) float floatx4;

__device__ __forceinline__ float sigf(float x) { return 1.0f / (1.0f + __expf(-x)); }
__device__ __forceinline__ float tanh_(float x) { return 1.0f - 2.0f / (1.0f + __expf(2.0f * x)); }

__device__ __forceinline__ u16 f2bf(float x) {
    u32 u = __float_as_uint(x);
    u32 r = (u + 0x7FFFu + ((u >> 16) & 1u)) >> 16;   // RNE
    return (u16)r;
}

// X [B,T,N] fp32 -> Xb [T,B,N] bf16
__global__ __launch_bounds__(256) void k_xb(const float* __restrict__ X, u16* __restrict__ Xb) {
    int i = blockIdx.x * 256 + threadIdx.x;
    int n = i & 127, b = (i >> 7) & 63, t = i >> 13;
    Xb[i] = f2bf(X[(b * T_ + t) * N_ + n]);
}

// Wcat^T [2048 cols][640 k] bf16: rows k<512 from Wh, k>=512 from Wx
__global__ __launch_bounds__(256) void k_wcat(const float* __restrict__ Wx, const float* __restrict__ Wh,
                                              u16* __restrict__ Wt) {
    int i = blockIdx.x * 256 + threadIdx.x;
    int c = i & 2047, k = i >> 11;
    float v = (k < H_) ? Wh[k * 2048 + c] : Wx[(k - H_) * 2048 + c];
    Wt[c * KDIM + k] = f2bf(v);
}

// XCD-local redundant LSTM. Every XCD computes the FULL recurrence (identical,
// deterministic), so all cross-WG traffic stays in that XCD's L2:
//   h stores: plain (vL1 write-through -> L2). flags: plain store to per-XCD
//   lines; consumers poll with sc0 loads (bypass own L1, hit shared L2).
//   Fallback: LLC flags via agent atomics if sc0 poll times out.
// WGs discover their XCD via HW_REG_XCC_ID and self-assign slots 0..31;
// incomplete XCDs exit without writing (correctness never assumes placement).
__global__ __launch_bounds__(256, 1) void k_lstm(const u16* __restrict__ Wt, const u16* __restrict__ Xb,
                                                 u16* __restrict__ hs, const float* __restrict__ bias,
                                                 u32* __restrict__ sync) {
    __shared__ u16 sW[64 * PITCH];     // 64-col weight slice, 82,944B
    __shared__ float sG[64 * SGP];     // gates, 16,640B
    __shared__ float sB[64];
    __shared__ int sSlot, sXcc;

    const int tid = threadIdx.x;
    const int lane = tid & 63, wv = tid >> 6;
    const int l16 = lane & 15, quad = lane >> 4;

    // ---- one-time: XCD self-organization ----
    if (tid == 0) {
        u32 xcc;
        asm volatile("s_getreg_b32 %0, hwreg(HW_REG_XCC_ID)" : "=s"(xcc));
        xcc &= 7;
        u32 slot = __hip_atomic_fetch_add(sync + xcc * FL, 1u, __ATOMIC_RELAXED, __HIP_MEMORY_SCOPE_AGENT);
        int ok = -1;
        if (slot < NSLOT) {
            int g = 0;
            while (__hip_atomic_load(sync + xcc * FL, __ATOMIC_RELAXED, __HIP_MEMORY_SCOPE_AGENT) < (u32)NSLOT) {
                __builtin_amdgcn_s_sleep(8);
                if (++g > 2000000) { ok = -2; break; }   // incomplete XCD: bail out safely
            }
            if (ok == -1) ok = (int)slot;
        }
        sSlot = ok; sXcc = (int)xcc;
    }
    __syncthreads();
    const int s = sSlot;
    if (s < 0) return;                  // extra WG or incomplete XCD
    const int xcc = sXcc;

    // ---- one-time: weight slice -> LDS. local col lc = n*16+cc -> global n*512 + s*16 + cc
    for (int u = tid; u < 64 * 80; u += 256) {
        int lc = u / 80, ch = u - lc * 80;
        int gc = (lc >> 4) * H_ + s * 16 + (lc & 15);
        short8 v = *(const short8*)(Wt + (size_t)gc * KDIM + ch * 8);
        *(short8*)(sW + lc * PITCH + ch * 8) = v;
    }
    if (tid < 64) {
        int gc = (tid >> 4) * H_ + s * 16 + (tid & 15);
        sB[tid] = bias[gc] + (((tid >> 4) == 2) ? 1.0f : 0.0f);   // fold forget_bias into f
    }
    __syncthreads();

    // gate-math mapping: thread owns batch gb, 4 local h-cols hh..hh+3
    const int gb = tid >> 2;            // = 16*wv + (lane>>2)
    const int hh = (tid & 3) * 4;
    float c0 = 0.f, c1 = 0.f, c2 = 0.f, c3 = 0.f;

    volatile u32* lfl = sync + (LF_BASE + xcc * NSLOT + s) * FL;
    u32* gfl = sync + (GF_BASE + xcc * NSLOT + s) * FL;
    const u32* pollp = sync + (LF_BASE + xcc * NSLOT + (lane & 31)) * FL;

    for (int t = 0; t < T_; ++t) {
        // x fragments (independent of recurrence) — issue before the wait
        short8 xfr[4];
        const u16* xrow = Xb + (size_t)t * (64 * N_) + (16 * wv + l16) * N_ + quad * 8;
#pragma unroll
        for (int ks = 0; ks < 4; ++ks) xfr[ks] = *(const short8*)(xrow + ks * 32);

        if (t > 0) {
            // phase 1: poll the 32 per-XCD L2 flags with sc0 loads (L1 bypass)
            int g = 0; bool timedout = false;
            for (;;) {
                u32 fv;
                asm volatile("global_load_dword %0, %1, off sc0\n\ts_waitcnt vmcnt(0)"
                             : "=v"(fv) : "v"(pollp) : "memory");
                if (__all(fv >= (u32)t)) break;
                __builtin_amdgcn_s_sleep(1);
                if (++g > 3000) { timedout = true; break; }
            }
            if (timedout) {
                // phase 2 (slow, proven): LLC flags via agent atomics
                const u32* gp = sync + (GF_BASE + xcc * NSLOT + (lane & 31)) * FL;
                int g2 = 0;
                while (__hip_atomic_load(gp, __ATOMIC_RELAXED, __HIP_MEMORY_SCOPE_AGENT) < (u32)t) {
                    __builtin_amdgcn_s_sleep(2);
                    if (++g2 > 500000) break;   // fail-safe: never hang
                }
            }
            asm volatile("" ::: "memory");
        }

        // h fragments: NORMAL vector loads. Fresh addresses every step -> L1 miss
        // guaranteed -> served by this XCD's L2 (where producers just wrote).
        short8 afr[16];
        const u16* hrow = hs + (size_t)t * (64 * H_) + (16 * wv + l16) * H_ + quad * 8;
#pragma unroll
        for (int ks = 0; ks < 16; ++ks) afr[ks] = *(const short8*)(hrow + ks * 32);

        // GEMM: M=16 rows (this wave), N=64 cols (4 ntiles), K=640; B streamed from LDS
        floatx4 acc[4];
#pragma unroll
        for (int n = 0; n < 4; ++n) acc[n] = (floatx4){0.f, 0.f, 0.f, 0.f};
        const u16* bbase = sW + l16 * PITCH + quad * 8;
#pragma unroll
        for (int ks = 0; ks < 16; ++ks) {
            short8 a = afr[ks];
#pragma unroll
            for (int n = 0; n < 4; ++n) {
                short8 b = *(const short8*)(bbase + n * (16 * PITCH) + ks * 32);
                acc[n] = __builtin_amdgcn_mfma_f32_16x16x32_bf16(a, b, acc[n], 0, 0, 0);
            }
        }
#pragma unroll
        for (int ks = 16; ks < 20; ++ks) {
            short8 a = xfr[ks - 16];
#pragma unroll
            for (int n = 0; n < 4; ++n) {
                short8 b = *(const short8*)(bbase + n * (16 * PITCH) + ks * 32);
                acc[n] = __builtin_amdgcn_mfma_f32_16x16x32_bf16(a, b, acc[n], 0, 0, 0);
            }
        }

        // C/D: col = lane&15 (within ntile), row = quad*4 + reg. Wave-private sG rows.
        int gbr = 16 * wv + quad * 4;
#pragma unroll
        for (int n = 0; n < 4; ++n)
#pragma unroll
            for (int r = 0; r < 4; ++r)
                sG[(gbr + r) * SGP + n * 16 + l16] = acc[n][r];
        asm volatile("s_waitcnt lgkmcnt(0)" ::: "memory");

        // gate math: local cols [i:0..15 | j:16..31 | f:32..47 | o:48..63]
        float h4[4];
        float* cc[4] = { &c0, &c1, &c2, &c3 };
#pragma unroll
        for (int j = 0; j < 4; ++j) {
            float iv = sG[gb * SGP + hh + j]      + sB[hh + j];
            float jv = sG[gb * SGP + 16 + hh + j] + sB[16 + hh + j];
            float fv = sG[gb * SGP + 32 + hh + j] + sB[32 + hh + j];
            float ov = sG[gb * SGP + 48 + hh + j] + sB[48 + hh + j];
            float c = sigf(fv) * (*cc[j]) + sigf(iv) * tanh_(jv);
            *cc[j] = c;
            h4[j] = sigf(ov) * tanh_(c);
        }
        u32 p0 = ((u32)f2bf(h4[1]) << 16) | (u32)f2bf(h4[0]);
        u32 p1 = ((u32)f2bf(h4[3]) << 16) | (u32)f2bf(h4[2]);
        u64 pk = ((u64)p1 << 32) | (u64)p0;
        // plain store: write-through vL1 -> this XCD's L2 (identical values in all XCDs)
        *(u64*)(hs + (size_t)(t + 1) * (64 * H_) + gb * H_ + s * 16 + hh) = pk;

        // drain to L2, join 4 waves, publish flags (L2 + LLC-fallback)
        asm volatile("s_waitcnt vmcnt(0)" ::: "memory");
        __syncthreads();
        if (tid == 0) {
            *lfl = (u32)(t + 1);        // plain -> L2 (sc0 pollers)
            __hip_atomic_store(gfl, (u32)(t + 1), __ATOMIC_RELAXED, __HIP_MEMORY_SCOPE_AGENT);
        }
    }
}

// decoder + loss: rows R = t*64+b of hs[1..512]; 32 rows/block staged in LDS
__global__ __launch_bounds__(256) void k_dec(const u16* __restrict__ hs, const float* __restrict__ Wd,
                                             const float* __restrict__ bd, const float* __restrict__ Y,
                                             float* __restrict__ out) {
    __shared__ u16 sH[32 * H_];
    __shared__ float red[4];
    int tid = threadIdx.x;
    int R0 = blockIdx.x * 32;
    for (int u = tid; u < 2048; u += 256) {
        int row = u >> 6, ch = u & 63;
        *(short8*)(sH + row * H_ + ch * 8) =
            *(const short8*)(hs + (size_t)(64 + R0 + row) * H_ + ch * 8);
    }
    __syncthreads();

    int n = tid & 127, half = tid >> 7;
    float bdv = bd[n];
    float acc[16];
#pragma unroll
    for (int i = 0; i < 16; ++i) acc[i] = 0.f;

    for (int ko = 0; ko < H_ / 8; ++ko) {
        float wv[8];
#pragma unroll
        for (int j = 0; j < 8; ++j) wv[j] = Wd[(ko * 8 + j) * N_ + n];
#pragma unroll
        for (int i = 0; i < 16; ++i) {
            int r = half * 16 + i;
            const uint4 hv = *(const uint4*)(sH + r * H_ + ko * 8);
            acc[i] += __uint_as_float(hv.x << 16) * wv[0] + __uint_as_float(hv.x & 0xFFFF0000u) * wv[1]
                    + __uint_as_float(hv.y << 16) * wv[2] + __uint_as_float(hv.y & 0xFFFF0000u) * wv[3]
                    + __uint_as_float(hv.z << 16) * wv[4] + __uint_as_float(hv.z & 0xFFFF0000u) * wv[5]
                    + __uint_as_float(hv.w << 16) * wv[6] + __uint_as_float(hv.w & 0xFFFF0000u) * wv[7];
        }
    }
    float sse = 0.f;
#pragma unroll
    for (int i = 0; i < 16; ++i) {
        int R = R0 + half * 16 + i;
        int t = R >> 6, b = R & 63;
        float logit = sigf(acc[i] + bdv);
        float d = Y[(size_t)(b * T_ + t) * N_ + n] - logit;
        sse += d * d;
    }
    for (int off = 32; off > 0; off >>= 1) sse += __shfl_down(sse, off, 64);
    if ((tid & 63) == 0) red[tid >> 6] = sse;
    __syncthreads();
    if (tid == 0) {
        float tot = red[0] + red[1] + red[2] + red[3];
        atomicAdd(out, tot * (100.0f / 4194304.0f));
    }
}

extern "C" void kernel_launch(void* const* d_in, const int* in_sizes, int n_in,
                              void* d_out, int out_size, void* d_ws, size_t ws_size,
                              hipStream_t stream) {
    (void)in_sizes; (void)n_in; (void)out_size;
    const float* X  = (const float*)d_in[0];
    const float* Y  = (const float*)d_in[1];
    const float* Wx = (const float*)d_in[2];
    const float* Wh = (const float*)d_in[3];
    const float* bb = (const float*)d_in[4];
    const float* Wd = (const float*)d_in[5];
    const float* bd = (const float*)d_in[6];

    char* ws = (char*)d_ws;
    u32* syncz = (u32*)ws;                                // 520 lines x 128B = 66,560B
    const size_t sync_bytes = 131072;
    u16* hs  = (u16*)(ws + sync_bytes);
    const size_t hs_bytes = (size_t)(T_ + 1) * 64 * H_ * 2;   // 33,619,968
    u16* Xb  = (u16*)(ws + sync_bytes + hs_bytes);
    const size_t xb_bytes = (size_t)T_ * 64 * N_ * 2;         // 8,388,608
    u16* Wt  = (u16*)(ws + sync_bytes + hs_bytes + xb_bytes);
    const size_t need = sync_bytes + hs_bytes + xb_bytes + (size_t)2048 * KDIM * 2;
    if (ws_size < need) return;   // ~44.8 MB scratch required

    (void)hipMemsetAsync(syncz, 0, 66560, stream);            // org counters + all flags
    (void)hipMemsetAsync(hs, 0, 64 * H_ * 2, stream);         // h_{-1} = 0
    (void)hipMemsetAsync(d_out, 0, sizeof(float), stream);

    k_xb<<<dim3((B_ * T_ * N_) / 256), dim3(256), 0, stream>>>(X, Xb);
    k_wcat<<<dim3((2048 * KDIM) / 256), dim3(256), 0, stream>>>(Wx, Wh, Wt);

    void* args[] = { (void*)&Wt, (void*)&Xb, (void*)&hs, (void*)&bb, (void*)&syncz };
    (void)hipLaunchCooperativeKernel((const void*)k_lstm, dim3(256), dim3(256), args, 0, stream);

    k_dec<<<dim3((B_ * T_) / 32), dim3(256), 0, stream>>>(hs, Wd, bd, Y, (float*)d_out);
}

// Round 8
// 2372.948 us; speedup vs baseline: 38.5149x; 38.5149x over previous
//
#include <hip/hip_runtime.h>
#include <stdint.h>

typedef unsigned short u16;
typedef unsigned int u32;
typedef unsigned long long u64;

#define B_ 64
#define T_ 512
#define N_ 128
#define H_ 512
#define KDIM 640        // H + N
#define SGW 65          // sG row pitch (fp32)
#define NSLOT 32        // WGs (column slots) per XCD
#define FL 32           // u32 per 128B line
// sync lines: [0..7] org counters (agent/LLC); [8..39] epoch sub-counters (L2-local), 4 per XCD

typedef __attribute__((ext_vector_type(8))) short short8;
typedef __attribute__((ext_vector_type(4))) float floatx4;

__device__ __forceinline__ float sigf(float x) { return 1.0f / (1.0f + __expf(-x)); }
__device__ __forceinline__ float tanh_(float x) { return 1.0f - 2.0f / (1.0f + __expf(2.0f * x)); }

__device__ __forceinline__ u16 f2bf(float x) {
    u32 u = __float_as_uint(x);
    u32 r = (u + 0x7FFFu + ((u >> 16) & 1u)) >> 16;   // RNE
    return (u16)r;
}

// X [B,T,N] fp32 -> Xb [T,B,N] bf16
__global__ __launch_bounds__(256) void k_xb(const float* __restrict__ X, u16* __restrict__ Xb) {
    int i = blockIdx.x * 256 + threadIdx.x;
    int n = i & 127, b = (i >> 7) & 63, t = i >> 13;
    Xb[i] = f2bf(X[(b * T_ + t) * N_ + n]);
}

// Wcat^T [2048 cols][640 k] bf16: rows k<512 from Wh, k>=512 from Wx
__global__ __launch_bounds__(256) void k_wcat(const float* __restrict__ Wx, const float* __restrict__ Wh,
                                              u16* __restrict__ Wt) {
    int i = blockIdx.x * 256 + threadIdx.x;
    int c = i & 2047, k = i >> 11;
    float v = (k < H_) ? Wh[k * 2048 + c] : Wx[(k - H_) * 2048 + c];
    Wt[c * KDIM + k] = f2bf(v);
}

// Batch-partitioned XCD-local LSTM. XCD x owns batches [8x, 8x+8) — batches are
// independent in the recurrence, so NO cross-XCD traffic exists. Within an XCD,
// slot s (one WG) computes h-cols [16s,16s+16) for those 8 batches; wave wv of
// the WG computes gate wv (16 cols), weights held entirely in VGPRs (20 frags).
// h exchange: plain stores/loads through the XCD's L2 (R7-proven correct).
// Sync: 4 L2-local atomic sub-epoch counters per XCD (RMW — return value can't
// be stale, unlike R7's sc0 loads). Wave0 polls; waves 1-3 spin on LDS epoch.
__global__ __launch_bounds__(256, 1) void k_lstm(const u16* __restrict__ Wt, const u16* __restrict__ Xb,
                                                 u16* __restrict__ hs, const float* __restrict__ bias,
                                                 u32* __restrict__ sync) {
    __shared__ float sG[16 * SGW];     // 16 M-rows x 64 gate-cols (+pad), 4160B
    __shared__ float sB[64];
    __shared__ int sSlot, sXcc, sEpoch;

    const int tid = threadIdx.x;
    const int lane = tid & 63, wv = tid >> 6;
    const int l16 = lane & 15, quad = lane >> 4;

    // ---- one-time: XCD self-organization (agent-scope; R7-proven) ----
    if (tid == 0) {
        u32 xcc;
        asm volatile("s_getreg_b32 %0, hwreg(HW_REG_XCC_ID)" : "=s"(xcc));
        xcc &= 7;
        u32 slot = __hip_atomic_fetch_add(sync + xcc * FL, 1u, __ATOMIC_RELAXED, __HIP_MEMORY_SCOPE_AGENT);
        int ok = -1;
        if (slot < NSLOT) {
            int g = 0;
            while (__hip_atomic_load(sync + xcc * FL, __ATOMIC_RELAXED, __HIP_MEMORY_SCOPE_AGENT) < (u32)NSLOT) {
                __builtin_amdgcn_s_sleep(8);
                if (++g > 2000000) { ok = -2; break; }
            }
            if (ok == -1) ok = (int)slot;
        }
        sSlot = ok; sXcc = (int)xcc; sEpoch = 0;
    }
    __syncthreads();
    const int s = sSlot;
    if (s < 0) return;                  // extra WG / incomplete XCD (never seen in R7)
    const int xcc = sXcc;
    const int b0 = 8 * xcc;             // this XCD's batch base

    if (tid < 64) {
        int gc = (tid >> 4) * H_ + s * 16 + (tid & 15);
        sB[tid] = bias[gc] + (((tid >> 4) == 2) ? 1.0f : 0.0f);   // fold forget_bias into f
    }

    // ---- one-time: full weight slice into VGPRs (wave wv = gate wv, col s*16+l16)
    short8 bfr[20];
    {
        const u16* wcol = Wt + (size_t)(wv * H_ + s * 16 + l16) * KDIM + quad * 8;
#pragma unroll
        for (int ks = 0; ks < 20; ++ks) bfr[ks] = *(const short8*)(wcol + ks * 32);
    }
    __syncthreads();

    // wave0 gate-math state: lane owns (batch b = lane>>3, col pair 2*(lane&7))
    float c0 = 0.f, c1 = 0.f;
    u32* epbase = sync + (size_t)(8 + xcc * 4) * FL;

    for (int t = 0; t < T_; ++t) {
        // x fragments (recurrence-independent): issue before the wait
        short8 xfr[4];
        const u16* xrow = Xb + ((size_t)t * 64 + b0 + (l16 & 7)) * N_ + quad * 8;
#pragma unroll
        for (int ks = 0; ks < 4; ++ks) xfr[ks] = *(const short8*)(xrow + ks * 32);

        if (t > 0) {
            if (wv == 0) {
                // poll 4 sub-epoch counters with L2-local atomic RMW (+0 -> current value)
                bool done = (lane >= 4);
                const u32 thr = 8u * (u32)t;
                u32* ep = epbase + (size_t)(lane & 3) * FL;
                int g = 0;
                for (;;) {
                    if (!done) {
                        u32 old, zero = 0;
                        asm volatile("global_atomic_add %0, %1, %2, off sc0\n\ts_waitcnt vmcnt(0)"
                                     : "=v"(old) : "v"(ep), "v"(zero) : "memory");
                        done = (old >= thr);
                    }
                    if (__all(done)) break;
                    __builtin_amdgcn_s_sleep(4);
                    if (++g > 300000) break;   // fail-safe: never hang the bench
                }
                __hip_atomic_store(&sEpoch, t, __ATOMIC_RELAXED, __HIP_MEMORY_SCOPE_WORKGROUP);
            } else {
                int g = 0;
                while (__hip_atomic_load(&sEpoch, __ATOMIC_RELAXED, __HIP_MEMORY_SCOPE_WORKGROUP) < t) {
                    __builtin_amdgcn_s_sleep(1);
                    if (++g > 2000000) break;
                }
            }
            asm volatile("" ::: "memory");     // no h-load motion above the wait
        }

        // h fragments: plain loads, served by this XCD's L2 (fresh addresses each t;
        // all 4 waves read the same 8KB -> L0 broadcast after first fill)
        short8 afr[16];
        const u16* hrow = hs + ((size_t)t * 64 + b0 + (l16 & 7)) * H_ + quad * 8;
#pragma unroll
        for (int ks = 0; ks < 16; ++ks) afr[ks] = *(const short8*)(hrow + ks * 32);

        // GEMM: M=16 (8 real batches duplicated), N=16 (this wave's gate cols), K=640
        floatx4 p = {0.f,0.f,0.f,0.f}, q = {0.f,0.f,0.f,0.f};
#pragma unroll
        for (int ks = 0; ks < 16; ks += 2) {
            p = __builtin_amdgcn_mfma_f32_16x16x32_bf16(afr[ks],     bfr[ks],     p, 0, 0, 0);
            q = __builtin_amdgcn_mfma_f32_16x16x32_bf16(afr[ks + 1], bfr[ks + 1], q, 0, 0, 0);
        }
#pragma unroll
        for (int ks = 0; ks < 4; ks += 2) {
            p = __builtin_amdgcn_mfma_f32_16x16x32_bf16(xfr[ks],     bfr[16 + ks],     p, 0, 0, 0);
            q = __builtin_amdgcn_mfma_f32_16x16x32_bf16(xfr[ks + 1], bfr[16 + ks + 1], q, 0, 0, 0);
        }
        floatx4 acc = p + q;

        // C/D: col = lane&15, row = quad*4 + r (rows 0..7 are the real batches)
#pragma unroll
        for (int r = 0; r < 4; ++r)
            sG[(quad * 4 + r) * SGW + wv * 16 + l16] = acc[r];
        __syncthreads();   // all gates of all waves visible

        if (wv == 0) {
            // gate math: lane -> batch b, cols 2cp, 2cp+1 of this slot
            int b = lane >> 3, cp = lane & 7;
            const float* gr = sG + b * SGW;
            int c0i = 2 * cp, c1i = 2 * cp + 1;
            float iv0 = gr[c0i]      + sB[c0i],      iv1 = gr[c1i]      + sB[c1i];
            float jv0 = gr[16 + c0i] + sB[16 + c0i], jv1 = gr[16 + c1i] + sB[16 + c1i];
            float fv0 = gr[32 + c0i] + sB[32 + c0i], fv1 = gr[32 + c1i] + sB[32 + c1i];
            float ov0 = gr[48 + c0i] + sB[48 + c0i], ov1 = gr[48 + c1i] + sB[48 + c1i];

            c0 = sigf(fv0) * c0 + sigf(iv0) * tanh_(jv0);
            c1 = sigf(fv1) * c1 + sigf(iv1) * tanh_(jv1);
            float h0 = sigf(ov0) * tanh_(c0);
            float h1 = sigf(ov1) * tanh_(c1);
            u32 pk = ((u32)f2bf(h1) << 16) | (u32)f2bf(h0);
            *(u32*)(hs + ((size_t)(t + 1) * 64 + b0 + b) * H_ + s * 16 + 2 * cp) = pk;

            // drain to L2, then L2-local epoch increment (sub-line s&3)
            asm volatile("s_waitcnt vmcnt(0)" ::: "memory");
            if (lane == 0) {
                u32 one = 1;
                u32* ep = epbase + (size_t)(s & 3) * FL;
                asm volatile("global_atomic_add %0, %1, off" :: "v"(ep), "v"(one) : "memory");
            }
        }
        // waves 1-3 run ahead; they re-gate at the next step's sEpoch spin,
        // which wave0 only publishes after its sG reads -> no sG WAR hazard.
    }
}

// decoder + loss: rows R = t*64+b of hs[1..512]; 32 rows/block staged in LDS
__global__ __launch_bounds__(256) void k_dec(const u16* __restrict__ hs, const float* __restrict__ Wd,
                                             const float* __restrict__ bd, const float* __restrict__ Y,
                                             float* __restrict__ out) {
    __shared__ u16 sH[32 * H_];
    __shared__ float red[4];
    int tid = threadIdx.x;
    int R0 = blockIdx.x * 32;
    for (int u = tid; u < 2048; u += 256) {
        int row = u >> 6, ch = u & 63;
        *(short8*)(sH + row * H_ + ch * 8) =
            *(const short8*)(hs + (size_t)(64 + R0 + row) * H_ + ch * 8);
    }
    __syncthreads();

    int n = tid & 127, half = tid >> 7;
    float bdv = bd[n];
    float acc[16];
#pragma unroll
    for (int i = 0; i < 16; ++i) acc[i] = 0.f;

    for (int ko = 0; ko < H_ / 8; ++ko) {
        float wv[8];
#pragma unroll
        for (int j = 0; j < 8; ++j) wv[j] = Wd[(ko * 8 + j) * N_ + n];
#pragma unroll
        for (int i = 0; i < 16; ++i) {
            int r = half * 16 + i;
            const uint4 hv = *(const uint4*)(sH + r * H_ + ko * 8);
            acc[i] += __uint_as_float(hv.x << 16) * wv[0] + __uint_as_float(hv.x & 0xFFFF0000u) * wv[1]
                    + __uint_as_float(hv.y << 16) * wv[2] + __uint_as_float(hv.y & 0xFFFF0000u) * wv[3]
                    + __uint_as_float(hv.z << 16) * wv[4] + __uint_as_float(hv.z & 0xFFFF0000u) * wv[5]
                    + __uint_as_float(hv.w << 16) * wv[6] + __uint_as_float(hv.w & 0xFFFF0000u) * wv[7];
        }
    }
    float sse = 0.f;
#pragma unroll
    for (int i = 0; i < 16; ++i) {
        int R = R0 + half * 16 + i;
        int t = R >> 6, b = R & 63;
        float logit = sigf(acc[i] + bdv);
        float d = Y[(size_t)(b * T_ + t) * N_ + n] - logit;
        sse += d * d;
    }
    for (int off = 32; off > 0; off >>= 1) sse += __shfl_down(sse, off, 64);
    if ((tid & 63) == 0) red[tid >> 6] = sse;
    __syncthreads();
    if (tid == 0) {
        float tot = red[0] + red[1] + red[2] + red[3];
        atomicAdd(out, tot * (100.0f / 4194304.0f));
    }
}

extern "C" void kernel_launch(void* const* d_in, const int* in_sizes, int n_in,
                              void* d_out, int out_size, void* d_ws, size_t ws_size,
                              hipStream_t stream) {
    (void)in_sizes; (void)n_in; (void)out_size;
    const float* X  = (const float*)d_in[0];
    const float* Y  = (const float*)d_in[1];
    const float* Wx = (const float*)d_in[2];
    const float* Wh = (const float*)d_in[3];
    const float* bb = (const float*)d_in[4];
    const float* Wd = (const float*)d_in[5];
    const float* bd = (const float*)d_in[6];

    char* ws = (char*)d_ws;
    u32* syncz = (u32*)ws;                                // 40 lines x 128B = 5120B
    const size_t sync_bytes = 131072;
    u16* hs  = (u16*)(ws + sync_bytes);
    const size_t hs_bytes = (size_t)(T_ + 1) * 64 * H_ * 2;   // 33,619,968
    u16* Xb  = (u16*)(ws + sync_bytes + hs_bytes);
    const size_t xb_bytes = (size_t)T_ * 64 * N_ * 2;         // 8,388,608
    u16* Wt  = (u16*)(ws + sync_bytes + hs_bytes + xb_bytes);
    const size_t need = sync_bytes + hs_bytes + xb_bytes + (size_t)2048 * KDIM * 2;
    if (ws_size < need) return;   // ~44.8 MB scratch required

    (void)hipMemsetAsync(syncz, 0, 5120, stream);             // org + epoch counters
    (void)hipMemsetAsync(hs, 0, 64 * H_ * 2, stream);         // h_{-1} = 0
    (void)hipMemsetAsync(d_out, 0, sizeof(float), stream);

    k_xb<<<dim3((B_ * T_ * N_) / 256), dim3(256), 0, stream>>>(X, Xb);
    k_wcat<<<dim3((2048 * KDIM) / 256), dim3(256), 0, stream>>>(Wx, Wh, Wt);

    void* args[] = { (void*)&Wt, (void*)&Xb, (void*)&hs, (void*)&bb, (void*)&syncz };
    (void)hipLaunchCooperativeKernel((const void*)k_lstm, dim3(256), dim3(256), args, 0, stream);

    k_dec<<<dim3((B_ * T_) / 32), dim3(256), 0, stream>>>(hs, Wd, bd, Y, (float*)d_out);
}